// Round 7
// baseline (1130.069 us; speedup 1.0000x reference)
//
#include <hip/hip_runtime.h>

namespace {

constexpr int T_LEN = 2048;
constexpr int B_TOT = 2048;
constexpr int H1 = 36;
constexpr int WPB = 4;       // waves (=batches) per block
constexpr int BLOCK = 64 * WPB;
constexpr int LDSW = 128;    // fp16 slots per wave region: hh[64] + hr[64]

typedef _Float16 h16x2 __attribute__((ext_vector_type(2)));

__device__ __forceinline__ float fdot2(float wb, float hb, float acc) {
  return __builtin_amdgcn_fdot2(__builtin_bit_cast(h16x2, wb),
                                __builtin_bit_cast(h16x2, hb), acc, false);
}
__device__ __forceinline__ float pack2h(float a, float b) {
  h16x2 t = {(_Float16)a, (_Float16)b};
  return __builtin_bit_cast(float, t);
}
__device__ __forceinline__ float fexp2(float x) { return __builtin_amdgcn_exp2f(x); }
__device__ __forceinline__ float frcp(float x) { return __builtin_amdgcn_rcpf(x); }
__device__ __forceinline__ float tanh_fast(float x) {
  return fmaf(2.f, frcp(1.f + fexp2(x * -2.88539008f)), -1.f);  // 2*sigm(2x)-1
}

// Row-slot decomposition: 148 rows (144 = L1 gates g*36+u; 144..147 = L2 gates)
// spread as r = 64*slot + lane, slot<3. Max 54 weight dwords/lane.
__global__ __launch_bounds__(BLOCK)
__attribute__((amdgpu_waves_per_eu(2, 2))) void lstm2_kernel(
    const float* __restrict__ x, const float* __restrict__ Wih1,
    const float* __restrict__ Whh1, const float* __restrict__ bih1,
    const float* __restrict__ bhh1, const float* __restrict__ Wih2,
    const float* __restrict__ Whh2, const float* __restrict__ bih2,
    const float* __restrict__ bhh2, float* __restrict__ out)
{
  __shared__ __align__(16) _Float16 sh[WPB * LDSW];

  const int tid = threadIdx.x;
  const int w = tid >> 6;
  const int lane = tid & 63;
  const int batch = blockIdx.x * WPB + w;

  _Float16* hh = sh + w * LDSW;  // h1 fp16, slots 0..35 live (36..63 dump)
  _Float16* hr = hh + 64;        // relu(h1) fp16 for the L2 rows

  // ---- per-(slot,lane) row setup ----
  float w2[3][18];
  float wBv[3], biasv[3], es[3], am[3], aa[3];
#pragma unroll
  for (int s = 0; s < 3; ++s) {
    const int r = 64 * s + lane;
    const bool isL1 = r < 144;
    const bool isL2r = (r >= 144 && r < 148);
    const float* wr = isL1 ? (Whh1 + r * H1) : (isL2r ? (Wih2 + (r - 144) * H1) : nullptr);
#pragma unroll
    for (int k = 0; k < 18; ++k)
      w2[s][k] = wr ? pack2h(wr[2 * k], wr[2 * k + 1]) : 0.f;
    wBv[s] = isL1 ? Wih1[r] : (isL2r ? Whh2[r - 144] : 0.f);
    biasv[s] = isL1 ? (bih1[r] + bhh1[r]) : (isL2r ? (bih2[r - 144] + bhh2[r - 144]) : 0.f);
    const bool isTanh = (r >= 72 && r < 108) || (r == 146);  // G rows
    es[s] = isTanh ? -2.88539008f : -1.44269504f;
    am[s] = isTanh ? 2.f : 1.f;
    aa[s] = isTanh ? -1.f : 0.f;
  }

  // gather lane indices for the c1 update (valid for lanes u<36)
  const int u = lane;
  const int idxF = ((u < 28) ? (36 + u) : (u - 28)) & 63;
  const int idxG = (8 + u) & 63;
  const int idxO = ((u < 20) ? (44 + u) : (u - 20)) & 63;

  const char* rd01 = (const char*)hh;  // slots 0/1 read true h1
  const char* rd2 = (const char*)((lane >= 16 && lane < 20) ? hr : hh);  // L2 rows read relu

  const float* xp = x + (size_t)batch * T_LEN;
  float* outp = out + (size_t)batch * T_LEN;

  hh[lane] = (_Float16)0.f;
  hr[lane] = (_Float16)0.f;
  __builtin_amdgcn_wave_barrier();

  float c1 = 0.f, c2 = 0.f, h2rep = 0.f;
  float4 ov = make_float4(0.f, 0.f, 0.f, 0.f);

  auto substep = [&](float xv) {
    // LDS broadcast reads: 36 halves = 72 B (lanes 0..35 region only)
    const float4 f0 = *(const float4*)(rd01);
    const float4 f1 = *(const float4*)(rd01 + 16);
    const float4 f2_ = *(const float4*)(rd01 + 32);
    const float4 f3 = *(const float4*)(rd01 + 48);
    const float2 f4 = *(const float2*)(rd01 + 64);
    const float4 g0 = *(const float4*)(rd2);
    const float4 g1 = *(const float4*)(rd2 + 16);
    const float4 g2_ = *(const float4*)(rd2 + 32);
    const float4 g3 = *(const float4*)(rd2 + 48);
    const float2 g4 = *(const float2*)(rd2 + 64);
    const float f[18] = {f0.x, f0.y, f0.z, f0.w, f1.x, f1.y, f1.z, f1.w,
                         f2_.x, f2_.y, f2_.z, f2_.w, f3.x, f3.y, f3.z, f3.w,
                         f4.x, f4.y};
    const float g[18] = {g0.x, g0.y, g0.z, g0.w, g1.x, g1.y, g1.z, g1.w,
                         g2_.x, g2_.y, g2_.z, g2_.w, g3.x, g3.y, g3.z, g3.w,
                         g4.x, g4.y};

    float pre0 = fmaf(xv, wBv[0], biasv[0]);
    float pre1 = fmaf(xv, wBv[1], biasv[1]);
    const float xin2 = (lane >= 16) ? h2rep : xv;  // lanes 16..19 = L2 rows
    float pre2 = fmaf(xin2, wBv[2], biasv[2]);
#pragma unroll
    for (int k = 0; k < 18; ++k) {
      pre0 = fdot2(w2[0][k], f[k], pre0);
      pre1 = fdot2(w2[1][k], f[k], pre1);
      pre2 = fdot2(w2[2][k], g[k], pre2);
    }
    // lane-packed activations (per-lane consts: sigmoid or tanh)
    const float act0 = fmaf(am[0], frcp(1.f + fexp2(pre0 * es[0])), aa[0]);
    const float act1 = fmaf(am[1], frcp(1.f + fexp2(pre1 * es[1])), aa[1]);
    const float act2 = fmaf(am[2], frcp(1.f + fexp2(pre2 * es[2])), aa[2]);

    // gather gates to update lanes (u = lane < 36)
    const float vF = (lane < 8) ? act1 : act0;
    const float F = __shfl(vF, idxF);
    const float G = __shfl(act1, idxG);
    const float vO = (lane < 16) ? act2 : act1;
    const float O = __shfl(vO, idxO);
    const float I = act0;  // rows 0..35 = I rows, local

    // L2 gates (slot2 lanes 16..19) -> replicated on all lanes
    const float I2 = __shfl(act2, 16);
    const float F2 = __shfl(act2, 17);
    const float G2 = __shfl(act2, 18);
    const float O2 = __shfl(act2, 19);

    c1 = fmaf(F, c1, I * G);      // valid on lanes 0..35
    c2 = fmaf(F2, c2, I2 * G2);   // replicated, consistent on all lanes
    const float cm = (lane < 36) ? c1 : c2;
    const float th = tanh_fast(cm);        // shared tanh for c1 and c2
    const float Om = (lane < 36) ? O : O2;
    const float hm = Om * th;              // lanes<36: h1_u; lanes>=36: h2
    h2rep = __shfl(hm, 36);                // broadcast h2 to all lanes
    __builtin_amdgcn_wave_barrier();
    hh[lane] = (_Float16)hm;               // lanes>=36 -> dump slots (unread)
    hr[lane] = (_Float16)fmaxf(hm, 0.f);
    __builtin_amdgcn_wave_barrier();
  };

  // Peel t=0: computes h1_0; L2 path ran on pre-sequence garbage -> reset.
  float4 qc = *(const float4*)xp;  // x[0..3]
  substep(qc.x);
  c2 = 0.f;
  h2rep = 0.f;

  // Group m: substeps t0+1..t0+4; substep t emits out[t-1] (h2 of step t-1's h1).
  for (int t0 = 0; t0 < T_LEN; t0 += 4) {
    const int tn = (t0 + 8 <= T_LEN) ? (t0 + 4) : (T_LEN - 4);
    const float4 qn = *(const float4*)(xp + tn);
    substep(qc.y);
    ov.x = h2rep;
    substep(qc.z);
    ov.y = h2rep;
    substep(qc.w);
    ov.z = h2rep;
    substep(qn.x);  // t0+4; at t0=2044 stale x, L1 result discarded, L2 emits out[2047]
    ov.w = h2rep;
    if (lane == 0) *(float4*)(outp + t0) = ov;
    qc = qn;
  }
}

}  // namespace

extern "C" void kernel_launch(void* const* d_in, const int* in_sizes, int n_in,
                              void* d_out, int out_size, void* d_ws, size_t ws_size,
                              hipStream_t stream) {
  const float* x    = (const float*)d_in[0];
  const float* Wih1 = (const float*)d_in[1];
  const float* Whh1 = (const float*)d_in[2];
  const float* bih1 = (const float*)d_in[3];
  const float* bhh1 = (const float*)d_in[4];
  const float* Wih2 = (const float*)d_in[5];
  const float* Whh2 = (const float*)d_in[6];
  const float* bih2 = (const float*)d_in[7];
  const float* bhh2 = (const float*)d_in[8];
  float* out = (float*)d_out;

  dim3 grid(B_TOT / WPB);  // 512 blocks; 2/CU -> 8 waves/CU, barrier-free
  dim3 block(BLOCK);       // 4 autonomous waves (1 batch each)
  hipLaunchKernelGGL(lstm2_kernel, grid, block, 0, stream,
                     x, Wih1, Whh1, bih1, bhh1, Wih2, Whh2, bih2, bhh2, out);
}

// Round 8
// 912.445 us; speedup vs baseline: 1.2385x; 1.2385x over previous
//
#include <hip/hip_runtime.h>

namespace {

constexpr int T_LEN = 2048;
constexpr int B_TOT = 2048;
constexpr int H1 = 36;
constexpr int NB = 16;      // batches per block = MFMA N
constexpr int BLOCK = 640;  // 9 A-waves (M-tiles) + 1 L2 wave
constexpr int RS = 80;      // hT row stride in halves: 160B, 16B-aligned, bank-spread

typedef _Float16 f16x8 __attribute__((ext_vector_type(8)));
typedef _Float16 h16x2 __attribute__((ext_vector_type(2)));
typedef float f32x4 __attribute__((ext_vector_type(4)));

__device__ __forceinline__ float fdot2(float wb, float hb, float acc) {
#if __has_builtin(__builtin_amdgcn_fdot2)
  return __builtin_amdgcn_fdot2(__builtin_bit_cast(h16x2, wb),
                                __builtin_bit_cast(h16x2, hb), acc, false);
#else
  float d;
  asm("v_dot2_f32_f16 %0, %1, %2, %3" : "=v"(d) : "v"(wb), "v"(hb), "0"(acc));
  return d;
#endif
}
__device__ __forceinline__ float pack2h(float a, float b) {
  h16x2 t = {(_Float16)a, (_Float16)b};
  return __builtin_bit_cast(float, t);
}
template <int PAT>
__device__ __forceinline__ float swzf(float v) {  // quad-broadcast via ds_swizzle
  return __builtin_bit_cast(
      float, __builtin_amdgcn_ds_swizzle(__builtin_bit_cast(int, v), PAT));
}
__device__ __forceinline__ float fexp2(float x) { return __builtin_amdgcn_exp2f(x); }
__device__ __forceinline__ float frcp(float x) { return __builtin_amdgcn_rcpf(x); }
__device__ __forceinline__ float sigm(float x) { return frcp(1.f + fexp2(x * -1.44269504f)); }
__device__ __forceinline__ float tanh_fast(float x) {
  return fmaf(2.f, frcp(1.f + fexp2(x * -2.88539008f)), -1.f);  // 2*sigm(2x)-1
}

__global__ __launch_bounds__(BLOCK) void lstm2_kernel(
    const float* __restrict__ x, const float* __restrict__ Wih1,
    const float* __restrict__ Whh1, const float* __restrict__ bih1,
    const float* __restrict__ bhh1, const float* __restrict__ Wih2,
    const float* __restrict__ Whh2, const float* __restrict__ bih2,
    const float* __restrict__ bhh2, float* __restrict__ out)
{
  // lds[buf][0]=h1 fp16 (B-layout: [batch n][k=unit]), lds[buf][1]=relu(h1)
  __shared__ __align__(16) _Float16 lds[2][2][NB][RS];

  const int tid = threadIdx.x;
  const int wid = tid >> 6;
  const int lane = tid & 63;
  const int g0 = blockIdx.x * NB;
  const bool isA = wid < 9;

  for (int i = tid; i < 2 * 2 * NB * RS; i += BLOCK)
    ((_Float16*)lds)[i] = (_Float16)0.f;  // h_{-1}=0 and zero-pad k>=36
  __syncthreads();

  // ---- A-wave (tile wid: units u0..u0+3, all 4 gates, 16 batches) ----
  const int m = lane & 15;   // A: row index / B,C: batch col
  const int q = lane >> 4;   // A,B: k-group / C: row group
  f16x8 A0 = {}, A1 = {};
  float wxc[4] = {0, 0, 0, 0}, bxc[4] = {0, 0, 0, 0};
  float c1 = 0.f;
  const float* xc = nullptr;
  if (isA) {
    const int u0 = wid * 4;
    // A[mrow][k]: mrow = uloc*4+g  ->  original row r = g*36 + (u0+uloc)
    const int ra = (m & 3) * H1 + (u0 + (m >> 2));
#pragma unroll
    for (int j = 0; j < 8; ++j) {
      A0[j] = (_Float16)Whh1[ra * H1 + q * 8 + j];  // k = q*8+j <= 31 < 36
      const int k1 = 32 + q * 8 + j;
      A1[j] = (k1 < H1) ? (_Float16)Whh1[ra * H1 + k1] : (_Float16)0.f;
    }
    // C rows held by this lane: mrow = q*4+reg -> unit u0+q, gate reg
#pragma unroll
    for (int r = 0; r < 4; ++r) {
      const int rc = r * H1 + (u0 + q);
      wxc[r] = Wih1[rc];
      bxc[r] = bih1[rc] + bhh1[rc];
    }
    xc = x + (size_t)(g0 + m) * T_LEN;
  }

  // ---- L2 wave: lane = batch*4 + gate ----
  const int lb = lane >> 2, lg = lane & 3;
  float w2[18];
  float whg = 0.f, b2 = 0.f, c2 = 0.f, h2 = 0.f;
  float* outp = nullptr;
#pragma unroll
  for (int k = 0; k < 18; ++k) w2[k] = 0.f;
  if (!isA) {
    const float* wr = Wih2 + lg * H1;
#pragma unroll
    for (int k = 0; k < 18; ++k) w2[k] = pack2h(wr[2 * k], wr[2 * k + 1]);
    whg = Whh2[lg];
    b2 = bih2[lg] + bhh2[lg];
    outp = out + (size_t)(g0 + lb) * T_LEN;
  }

  float4 qx = make_float4(0.f, 0.f, 0.f, 0.f);
  if (isA) qx = *(const float4*)xc;  // x[0..3]
  float4 ov = make_float4(0.f, 0.f, 0.f, 0.f);

  // One iteration: A-waves compute h_i from h_{i-1}; L2 wave computes out[i-1].
  // Single barrier/step is safe: writes at iter i+1 target buf[(i+1)&1], which
  // iter i's reads (buf[(i+1)&1]... = its write buf? no: reads ib=(i+1)&1)
  // happen before the barrier at end of iter i.
  auto step = [&](int i, float xv, int s) {
    const int ib = (s + 1) & 1;  // holds h_{i-1}
    const int wb = s & 1;
    if (isA) {
      const f16x8 B0 = *(const f16x8*)&lds[ib][0][m][q * 8];        // k=q*8..+7
      const f16x8 B1 = *(const f16x8*)&lds[ib][0][m][32 + q * 8];   // zeros pad k>=36
      f32x4 cc;
#pragma unroll
      for (int r = 0; r < 4; ++r) cc[r] = fmaf(xv, wxc[r], bxc[r]);
      cc = __builtin_amdgcn_mfma_f32_16x16x32_f16(A0, B0, cc, 0, 0, 0);
      cc = __builtin_amdgcn_mfma_f32_16x16x32_f16(A1, B1, cc, 0, 0, 0);
      const float I = sigm(cc[0]), F = sigm(cc[1]);
      const float G = tanh_fast(cc[2]), O = sigm(cc[3]);
      c1 = fmaf(F, c1, I * G);
      const float h = O * tanh_fast(c1);
      const int ku = (wid << 2) + q;  // this lane's unit
      lds[wb][0][m][ku] = (_Float16)h;
      lds[wb][1][m][ku] = (_Float16)fmaxf(h, 0.f);
    } else if (i > 0) {
      const char* rp = (const char*)&lds[ib][1][lb][0];  // relu(h_{i-1}), row lb
      const float4 r0 = *(const float4*)rp;
      const float4 r1 = *(const float4*)(rp + 16);
      const float4 r2 = *(const float4*)(rp + 32);
      const float4 r3 = *(const float4*)(rp + 48);
      const float2 r4 = *(const float2*)(rp + 64);
      const float f[18] = {r0.x, r0.y, r0.z, r0.w, r1.x, r1.y, r1.z, r1.w,
                           r2.x, r2.y, r2.z, r2.w, r3.x, r3.y, r3.z, r3.w,
                           r4.x, r4.y};
      float aE = 0.f, aO = 0.f;  // two accs: halve the dot dep-chain
#pragma unroll
      for (int k = 0; k < 18; k += 2) aE = fdot2(w2[k], f[k], aE);
#pragma unroll
      for (int k = 1; k < 18; k += 2) aO = fdot2(w2[k], f[k], aO);
      const float pre = (aE + aO) + fmaf(h2, whg, b2);  // this lane's gate lg
      const float pI = swzf<0x8000 | 0x00>(pre);  // quad-broadcast lane 0 (i)
      const float pF = swzf<0x8000 | 0x55>(pre);  // lane 1 (f)
      const float pG = swzf<0x8000 | 0xAA>(pre);  // lane 2 (g)
      const float pO = swzf<0x8000 | 0xFF>(pre);  // lane 3 (o)
      c2 = fmaf(sigm(pF), c2, sigm(pI) * tanh_fast(pG));
      h2 = sigm(pO) * tanh_fast(c2);  // = out[i-1], replicated in quad
      if (s == 1) ov.x = h2;
      else if (s == 2) ov.y = h2;
      else if (s == 3) ov.z = h2;
      else {
        ov.w = h2;
        if (lg == 0) *(float4*)(outp + (i - 4)) = ov;  // out[i-4..i-1]
      }
    }
    __syncthreads();
  };

  for (int i0 = 0; i0 < T_LEN; i0 += 4) {
    float4 qn = qx;
    if (isA) {  // prefetch next x quad (clamped; tail value unused garbage-OK)
      const int tn = (i0 + 4 < T_LEN) ? (i0 + 4) : (T_LEN - 4);
      qn = *(const float4*)(xc + tn);
    }
    step(i0 + 0, qx.x, 0);
    step(i0 + 1, qx.y, 1);
    step(i0 + 2, qx.z, 2);
    step(i0 + 3, qx.w, 3);
    qx = qn;
  }
  // Final iter i=2048: A-waves compute a discarded h_2048; L2 emits out[2047]
  // and stores out[2044..2047].
  step(T_LEN, qx.x, 0);
}

}  // namespace

extern "C" void kernel_launch(void* const* d_in, const int* in_sizes, int n_in,
                              void* d_out, int out_size, void* d_ws, size_t ws_size,
                              hipStream_t stream) {
  const float* x    = (const float*)d_in[0];
  const float* Wih1 = (const float*)d_in[1];
  const float* Whh1 = (const float*)d_in[2];
  const float* bih1 = (const float*)d_in[3];
  const float* bhh1 = (const float*)d_in[4];
  const float* Wih2 = (const float*)d_in[5];
  const float* Whh2 = (const float*)d_in[6];
  const float* bih2 = (const float*)d_in[7];
  const float* bhh2 = (const float*)d_in[8];
  float* out = (float*)d_out;

  dim3 grid(B_TOT / NB);  // 128 blocks x 16 batches
  dim3 block(BLOCK);      // 9 MFMA waves + 1 L2 wave
  hipLaunchKernelGGL(lstm2_kernel, grid, block, 0, stream,
                     x, Wih1, Whh1, bih1, bhh1, Wih2, Whh2, bih2, bhh2, out);
}